// Round 2
// baseline (244.874 us; speedup 1.0000x reference)
//
#include <hip/hip_runtime.h>

// Rx(theta) on qubit 0 (MSB of state index) of a 24-qubit state.
// Inputs: state_re [2^24] f32, state_im [2^24] f32, theta [1] f32.
// Output: [2, 2^24] f32 = stack(out_re, out_im).
//
// R1 post-mortem: 84us @ 2.4TB/s HBM, VALUBusy 5%, occupancy 60% ->
// latency/MLP-bound, not BW-bound. R2: grid-stride, 4 unrolled iters/thread,
// all 16 loads in flight before compute (16x16B/lane outstanding).

constexpr int HALF   = 1 << 23;      // amplitudes per half
constexpr int NV     = HALF / 4;     // float4 work items = 2^21
constexpr int BLOCKS = 2048;
constexpr int THREADS = 256;
constexpr int GRIDSTRIDE = BLOCKS * THREADS;      // 2^19
constexpr int ITER   = NV / GRIDSTRIDE;           // 4

__global__ __launch_bounds__(THREADS) void rx_gate_kernel(
    const float4* __restrict__ sre,
    const float4* __restrict__ sim,
    const float*  __restrict__ theta,
    float4* __restrict__ out)
{
    const int base = blockIdx.x * THREADS + threadIdx.x;

    const float t2 = theta[0] * 0.5f;
    const float s = sinf(t2);
    const float c = cosf(t2);

    float4 a_re[ITER], a_im[ITER], b_re[ITER], b_im[ITER];

    // Issue ALL loads first -> 16 outstanding 16B loads per lane.
#pragma unroll
    for (int it = 0; it < ITER; ++it) {
        const int i = base + it * GRIDSTRIDE;
        a_re[it] = sre[i];
        a_im[it] = sim[i];
        b_re[it] = sre[i + NV];
        b_im[it] = sim[i + NV];
    }

#pragma unroll
    for (int it = 0; it < ITER; ++it) {
        const int i = base + it * GRIDSTRIDE;
        float4 o0_re, o0_im, o1_re, o1_im;

        o0_re.x = c * a_re[it].x + s * b_im[it].x;
        o0_re.y = c * a_re[it].y + s * b_im[it].y;
        o0_re.z = c * a_re[it].z + s * b_im[it].z;
        o0_re.w = c * a_re[it].w + s * b_im[it].w;

        o0_im.x = c * a_im[it].x - s * b_re[it].x;
        o0_im.y = c * a_im[it].y - s * b_re[it].y;
        o0_im.z = c * a_im[it].z - s * b_re[it].z;
        o0_im.w = c * a_im[it].w - s * b_re[it].w;

        o1_re.x = c * b_re[it].x + s * a_im[it].x;
        o1_re.y = c * b_re[it].y + s * a_im[it].y;
        o1_re.z = c * b_re[it].z + s * a_im[it].z;
        o1_re.w = c * b_re[it].w + s * a_im[it].w;

        o1_im.x = c * b_im[it].x - s * a_re[it].x;
        o1_im.y = c * b_im[it].y - s * a_re[it].y;
        o1_im.z = c * b_im[it].z - s * a_re[it].z;
        o1_im.w = c * b_im[it].w - s * a_re[it].w;

        // d_out layout (float4 units): [0:NV)=out0_re, [NV:2NV)=out1_re,
        // [2NV:3NV)=out0_im, [3NV:4NV)=out1_im
        out[i]          = o0_re;
        out[i + NV]     = o1_re;
        out[i + 2 * NV] = o0_im;
        out[i + 3 * NV] = o1_im;
    }
}

extern "C" void kernel_launch(void* const* d_in, const int* in_sizes, int n_in,
                              void* d_out, int out_size, void* d_ws, size_t ws_size,
                              hipStream_t stream) {
    const float4* sre   = (const float4*)d_in[0];
    const float4* sim   = (const float4*)d_in[1];
    const float*  theta = (const float*)d_in[2];
    float4* out = (float4*)d_out;

    rx_gate_kernel<<<BLOCKS, THREADS, 0, stream>>>(sre, sim, theta, out);
}

// Round 4
// 243.039 us; speedup vs baseline: 1.0075x; 1.0075x over previous
//
#include <hip/hip_runtime.h>

// Rx(theta) on qubit 0 (MSB of state index) of a 24-qubit state.
// Inputs: state_re [2^24] f32, state_im [2^24] f32, theta [1] f32.
// Output: [2, 2^24] f32 = stack(out_re, out_im).
//
// R1: one-shot 8192x256 blocks, 4+4 float4 streams -> 84us, 3.2 TB/s eff.
// R2 FAILED: grid-stride ILP (compiler serialized; no dispatch slack).
// R3 FAILED: compile — __builtin_nontemporal_store rejects HIP_vector_type.
// R4: same as R3 but with clang native ext_vector_type(4) float for the
//     nontemporal stores (and loads). nt writes stream past L2/L3 so they
//     stop evicting the L3-resident input lines.

typedef float v4f __attribute__((ext_vector_type(4)));

constexpr int HALF = 1 << 23;     // amplitudes per half
constexpr int NV   = HALF / 4;    // float4 work items = 2^21

__global__ __launch_bounds__(256) void rx_gate_kernel(
    const v4f* __restrict__ sre,
    const v4f* __restrict__ sim,
    const float* __restrict__ theta,
    v4f* __restrict__ out)
{
    const int i = blockIdx.x * blockDim.x + threadIdx.x;  // [0, NV)

    const float t2 = theta[0] * 0.5f;
    const float s = sinf(t2);
    const float c = cosf(t2);

    const v4f a_re = sre[i];
    const v4f a_im = sim[i];
    const v4f b_re = sre[i + NV];
    const v4f b_im = sim[i + NV];

    // Vector math on native ext_vector types (element-wise).
    const v4f o0_re = c * a_re + s * b_im;
    const v4f o0_im = c * a_im - s * b_re;
    const v4f o1_re = c * b_re + s * a_im;
    const v4f o1_im = c * b_im - s * a_re;

    // d_out layout (float4 units): [0:NV)=out0_re, [NV:2NV)=out1_re,
    // [2NV:3NV)=out0_im, [3NV:4NV)=out1_im.
    // Nontemporal: outputs are write-once, never re-read.
    __builtin_nontemporal_store(o0_re, &out[i]);
    __builtin_nontemporal_store(o1_re, &out[i + NV]);
    __builtin_nontemporal_store(o0_im, &out[i + 2 * NV]);
    __builtin_nontemporal_store(o1_im, &out[i + 3 * NV]);
}

extern "C" void kernel_launch(void* const* d_in, const int* in_sizes, int n_in,
                              void* d_out, int out_size, void* d_ws, size_t ws_size,
                              hipStream_t stream) {
    const v4f*  sre   = (const v4f*)d_in[0];
    const v4f*  sim   = (const v4f*)d_in[1];
    const float* theta = (const float*)d_in[2];
    v4f* out = (v4f*)d_out;

    const int threads = 256;
    const int blocks  = NV / threads;  // 8192, one-shot, 4x CU oversubscription
    rx_gate_kernel<<<blocks, threads, 0, stream>>>(sre, sim, theta, out);
}